// Round 1
// baseline (800.439 us; speedup 1.0000x reference)
//
#include <hip/hip_runtime.h>
#include <stdint.h>
#include <math.h>

#define H_ 16
#define HD_ 128
#define RD_ 64
#define CD_ 64
#define DM_ 2048
#define QR_ 512
#define DL_ 512
#define B_ 2
#define T_ 2048
#define M_TOT (B_*T_)

typedef __attribute__((ext_vector_type(8))) short short8;
typedef __attribute__((ext_vector_type(4))) float f32x4;

__device__ __forceinline__ unsigned short f2b(float f){
  union { float f; unsigned u; } a; a.f = f;
  unsigned r = a.u + 0x7fffu + ((a.u >> 16) & 1u);
  return (unsigned short)(r >> 16);
}
__device__ __forceinline__ float b2f(unsigned short b){
  union { unsigned u; float f; } a; a.u = ((unsigned)b) << 16;
  return a.f;
}

#define GLOAD16(g, l) __builtin_amdgcn_global_load_lds( \
    (__attribute__((address_space(1))) void*)(g), \
    (__attribute__((address_space(3))) void*)(l), 16, 0, 0)

// ---------------- cast f32 -> bf16 ----------------
__global__ void cast_f32_bf16(const float* __restrict__ src,
                              unsigned short* __restrict__ dst, int n){
  int i = (blockIdx.x * blockDim.x + threadIdx.x) * 4;
  if (i < n){
    float4 v = *(const float4*)(src + i);
    ushort4 o;
    o.x = f2b(v.x); o.y = f2b(v.y); o.z = f2b(v.z); o.w = f2b(v.w);
    *(ushort4*)(dst + i) = o;
  }
}

// ---------------- transpose + cast: W[K,N] f32 -> Wt[N,K] bf16 ----------------
__global__ void transpose_cast(const float* __restrict__ W,
                               unsigned short* __restrict__ Wt, int K, int N){
  __shared__ float tile[32][33];
  int n0 = blockIdx.x * 32, k0 = blockIdx.y * 32;
  int tx = threadIdx.x, ty = threadIdx.y; // (32,8)
  #pragma unroll
  for (int r = ty; r < 32; r += 8)
    tile[r][tx] = W[(size_t)(k0 + r) * N + n0 + tx];
  __syncthreads();
  #pragma unroll
  for (int r = ty; r < 32; r += 8)
    Wt[(size_t)(n0 + r) * K + k0 + tx] = f2b(tile[tx][r]);
}

// ---------------- GEMM: C[M,N] = A[M,K](bf16) @ Bt[N,K]^T (bf16) ----------------
// m97 structure: 128x128 tile, BK=32, 4 waves (2x2), global_load_lds width 16.
template<int OUTF32>
__global__ __launch_bounds__(256) void gemm_bt(
    const unsigned short* __restrict__ A,
    const unsigned short* __restrict__ Bt,
    void* __restrict__ Cv, int M, int N, int K)
{
  __shared__ unsigned short As[128 * 32];
  __shared__ unsigned short Bs[128 * 32];
  int tid = threadIdx.x;
  int m0 = blockIdx.y * 128, n0 = blockIdx.x * 128;
  int lane = tid & 63, w = tid >> 6;
  int wr = (w >> 1) * 64, wc = (w & 1) * 64;
  int mr = lane & 15, kg = lane >> 4;

  const unsigned short* Ag = A  + (size_t)(m0 + (tid >> 2)) * K + ((tid & 3) << 3);
  const unsigned short* Bg = Bt + (size_t)(n0 + (tid >> 2)) * K + ((tid & 3) << 3);

  f32x4 acc[4][4];
  #pragma unroll
  for (int i = 0; i < 4; i++)
    #pragma unroll
    for (int j = 0; j < 4; j++)
      acc[i][j] = (f32x4){0.f, 0.f, 0.f, 0.f};

  for (int k0 = 0; k0 < K; k0 += 32) {
    #pragma unroll
    for (int j = 0; j < 2; j++) {
      GLOAD16(Ag + (size_t)j * 64 * K, &As[j * 2048 + tid * 8]);
      GLOAD16(Bg + (size_t)j * 64 * K, &Bs[j * 2048 + tid * 8]);
    }
    Ag += 32; Bg += 32;
    __syncthreads();
    short8 af[4], bf[4];
    #pragma unroll
    for (int i = 0; i < 4; i++)
      af[i] = *(const short8*)&As[(wr + i * 16 + mr) * 32 + kg * 8];
    #pragma unroll
    for (int j = 0; j < 4; j++)
      bf[j] = *(const short8*)&Bs[(wc + j * 16 + mr) * 32 + kg * 8];
    #pragma unroll
    for (int i = 0; i < 4; i++)
      #pragma unroll
      for (int j = 0; j < 4; j++)
        acc[i][j] = __builtin_amdgcn_mfma_f32_16x16x32_bf16(af[i], bf[j], acc[i][j], 0, 0, 0);
    __syncthreads();
  }

  if (OUTF32) {
    float* C = (float*)Cv;
    #pragma unroll
    for (int i = 0; i < 4; i++)
      #pragma unroll
      for (int j = 0; j < 4; j++)
        #pragma unroll
        for (int r = 0; r < 4; r++) {
          int row = m0 + wr + i * 16 + kg * 4 + r;
          int col = n0 + wc + j * 16 + mr;
          C[(size_t)row * N + col] = acc[i][j][r];
        }
  } else {
    unsigned short* C = (unsigned short*)Cv;
    #pragma unroll
    for (int i = 0; i < 4; i++)
      #pragma unroll
      for (int j = 0; j < 4; j++)
        #pragma unroll
        for (int r = 0; r < 4; r++) {
          int row = m0 + wr + i * 16 + kg * 4 + r;
          int col = n0 + wc + j * 16 + mr;
          C[(size_t)row * N + col] = f2b(acc[i][j][r]);
        }
  }
}

// ---------------- assemble q,k head-major with RoPE ----------------
// qc/kc: [B*T, H*64] content; qp/kp: [B*T, H*64] pre-rope.
// out qh/kh: [B,H,T,128] (content | roped pos)
__global__ void assemble_qk(const unsigned short* __restrict__ qc,
                            const unsigned short* __restrict__ qp,
                            const unsigned short* __restrict__ kc,
                            const unsigned short* __restrict__ kp,
                            unsigned short* __restrict__ qh,
                            unsigned short* __restrict__ kh){
  int row = blockIdx.x * 2 + threadIdx.y;   // (b,h,t) flattened
  int d = threadIdx.x;                      // 0..127
  int bh = row >> 11;                       // /T_
  int t  = row & (T_ - 1);
  int b = bh / H_, h = bh % H_;
  size_t srow = (size_t)b * T_ + t;
  size_t dst = ((size_t)bh * T_ + t) * 128 + d;
  if (d < 64) {
    qh[dst] = qc[srow * (H_*CD_) + h * 64 + d];
    kh[dst] = kc[srow * (H_*CD_) + h * 64 + d];
  } else {
    int i = d - 64;
    int j = i & 31;
    // inv_freq = 10000^(-j/32) = exp2(-j * log2(10000)/32)
    float invf = exp2f(-(float)j * 0.4152410118750f);
    float f = (float)t * invf;
    float s, c;
    sincosf(f, &s, &c);
    float qx1 = b2f(qp[srow * (H_*RD_) + h * 64 + j]);
    float qx2 = b2f(qp[srow * (H_*RD_) + h * 64 + j + 32]);
    float kx1 = b2f(kp[srow * (H_*RD_) + h * 64 + j]);
    float kx2 = b2f(kp[srow * (H_*RD_) + h * 64 + j + 32]);
    float qv = (i < 32) ? (qx1 * c - qx2 * s) : (qx1 * s + qx2 * c);
    float kv = (i < 32) ? (kx1 * c - kx2 * s) : (kx1 * s + kx2 * c);
    qh[dst] = f2b(qv);
    kh[dst] = f2b(kv);
  }
}

// ---------------- transpose v: [B*T, H*128] -> vt [B,H,128,T] ----------------
__global__ void vtrans(const unsigned short* __restrict__ vbuf,
                       unsigned short* __restrict__ vt){
  __shared__ unsigned short tile[32][33];
  int bh = blockIdx.z;
  int b = bh / H_, h = bh % H_;
  const unsigned short* src = vbuf + (size_t)b * T_ * (H_*HD_) + h * HD_;
  unsigned short* dst = vt + (size_t)bh * HD_ * T_;
  int t0 = blockIdx.x * 32, d0 = blockIdx.y * 32;
  int tx = threadIdx.x, ty = threadIdx.y; // (32,8)
  #pragma unroll
  for (int r = ty; r < 32; r += 8)
    tile[r][tx] = src[(size_t)(t0 + r) * (H_*HD_) + d0 + tx];
  __syncthreads();
  #pragma unroll
  for (int r = ty; r < 32; r += 8)
    dst[(size_t)(d0 + r) * T_ + t0 + tx] = tile[tx][r];
}

// ---------------- causal flash attention ----------------
// qh,kh: [B,H,T,128]; vt: [B,H,128,T]; ao: [B*T, H*128]
// block = 4 waves; wave = 16 q rows; kv chunks of 32.
__global__ __launch_bounds__(256) void attn_fwd(
    const unsigned short* __restrict__ qh,
    const unsigned short* __restrict__ kh,
    const unsigned short* __restrict__ vt,
    unsigned short* __restrict__ ao)
{
  __shared__ unsigned short P[4][16 * 32];
  int tid = threadIdx.x, lane = tid & 63, w = tid >> 6;
  int mr = lane & 15, kg = lane >> 4;
  int bh = blockIdx.y, b = bh >> 4, h = bh & 15;
  int q0 = blockIdx.x * 64 + w * 16;
  const unsigned short* Q  = qh + (size_t)bh * T_ * 128;
  const unsigned short* Kb = kh + (size_t)bh * T_ * 128;
  const unsigned short* Vb = vt + (size_t)bh * 128 * T_;

  short8 qf[4];
  #pragma unroll
  for (int kc = 0; kc < 4; kc++)
    qf[kc] = *(const short8*)&Q[(size_t)(q0 + mr) * 128 + kc * 32 + kg * 8];

  f32x4 accO[8];
  #pragma unroll
  for (int d = 0; d < 8; d++) accO[d] = (f32x4){0.f, 0.f, 0.f, 0.f};
  float mrow[4] = {-3e38f, -3e38f, -3e38f, -3e38f};
  float lrow[4] = {0.f, 0.f, 0.f, 0.f};
  int qmax = q0 + 15;
  unsigned short* Pw = &P[w][0];

  for (int kv0 = 0; kv0 <= qmax; kv0 += 32) {
    f32x4 s0 = (f32x4){0.f,0.f,0.f,0.f}, s1 = (f32x4){0.f,0.f,0.f,0.f};
    #pragma unroll
    for (int kc = 0; kc < 4; kc++) {
      short8 kf0 = *(const short8*)&Kb[(size_t)(kv0 + mr) * 128 + kc * 32 + kg * 8];
      short8 kf1 = *(const short8*)&Kb[(size_t)(kv0 + 16 + mr) * 128 + kc * 32 + kg * 8];
      s0 = __builtin_amdgcn_mfma_f32_16x16x32_bf16(qf[kc], kf0, s0, 0, 0, 0);
      s1 = __builtin_amdgcn_mfma_f32_16x16x32_bf16(qf[kc], kf1, s1, 0, 0, 0);
    }
    const float scale = 0.08838834764831845f;
    float pm[4];
    #pragma unroll
    for (int r = 0; r < 4; r++) {
      int qrow = q0 + kg * 4 + r;
      float v0 = s0[r] * scale, v1 = s1[r] * scale;
      if (kv0 + mr > qrow) v0 = -1e30f;
      if (kv0 + 16 + mr > qrow) v1 = -1e30f;
      s0[r] = v0; s1[r] = v1;
      pm[r] = fmaxf(v0, v1);
    }
    #pragma unroll
    for (int off = 1; off < 16; off <<= 1)
      #pragma unroll
      for (int r = 0; r < 4; r++)
        pm[r] = fmaxf(pm[r], __shfl_xor(pm[r], off, 64));
    float ps[4];
    #pragma unroll
    for (int r = 0; r < 4; r++) {
      float mn = fmaxf(mrow[r], pm[r]);
      float fac = __expf(mrow[r] - mn);
      mrow[r] = mn;
      float p0 = __expf(s0[r] - mn), p1 = __expf(s1[r] - mn);
      s0[r] = p0; s1[r] = p1;
      ps[r] = p0 + p1;
      lrow[r] *= fac;
      #pragma unroll
      for (int d = 0; d < 8; d++) accO[d][r] *= fac;
    }
    #pragma unroll
    for (int off = 1; off < 16; off <<= 1)
      #pragma unroll
      for (int r = 0; r < 4; r++)
        ps[r] += __shfl_xor(ps[r], off, 64);
    #pragma unroll
    for (int r = 0; r < 4; r++) lrow[r] += ps[r];
    #pragma unroll
    for (int r = 0; r < 4; r++) {
      int prow = kg * 4 + r;
      Pw[prow * 32 + mr]      = f2b(s0[r]);
      Pw[prow * 32 + 16 + mr] = f2b(s1[r]);
    }
    short8 pa = *(const short8*)&Pw[mr * 32 + kg * 8];
    #pragma unroll
    for (int d = 0; d < 8; d++) {
      short8 vf = *(const short8*)&Vb[(size_t)(d * 16 + mr) * T_ + kv0 + kg * 8];
      accO[d] = __builtin_amdgcn_mfma_f32_16x16x32_bf16(pa, vf, accO[d], 0, 0, 0);
    }
  }

  #pragma unroll
  for (int d = 0; d < 8; d++)
    #pragma unroll
    for (int r = 0; r < 4; r++) {
      int qrow = q0 + kg * 4 + r;
      float o = accO[d][r] / lrow[r];
      ao[((size_t)b * T_ + qrow) * (H_*HD_) + h * 128 + d * 16 + mr] = f2b(o);
    }
}

// ---------------- launcher ----------------
extern "C" void kernel_launch(void* const* d_in, const int* in_sizes, int n_in,
                              void* d_out, int out_size, void* d_ws, size_t ws_size,
                              hipStream_t stream)
{
  (void)in_sizes; (void)n_in; (void)out_size; (void)ws_size;
  const float* x        = (const float*)d_in[0];
  const float* Wq_down  = (const float*)d_in[1];
  const float* Wq_up    = (const float*)d_in[2];
  const float* Wq_rope  = (const float*)d_in[3];
  const float* Wkv_down = (const float*)d_in[4];
  const float* Wk_up    = (const float*)d_in[5];
  const float* Wv_up    = (const float*)d_in[6];
  const float* Wk_rope  = (const float*)d_in[7];
  const float* Wo       = (const float*)d_in[8];

  char* ws = (char*)d_ws;
  unsigned short* xb     = (unsigned short*)(ws + 0);          // 16 MB
  unsigned short* WqdT   = (unsigned short*)(ws + 16777216);   // [512,2048]  2 MB
  unsigned short* WquT   = (unsigned short*)(ws + 18874368);   // [1024,512]  1 MB
  unsigned short* WqrT   = (unsigned short*)(ws + 19922944);   // [1024,2048] 4 MB
  unsigned short* WkvdT  = (unsigned short*)(ws + 24117248);   // [512,2048]  2 MB
  unsigned short* WkuT   = (unsigned short*)(ws + 26214400);   // [1024,512]  1 MB
  unsigned short* WvuT   = (unsigned short*)(ws + 27262976);   // [2048,512]  2 MB
  unsigned short* WkrT   = (unsigned short*)(ws + 29360128);   // [1024,2048] 4 MB
  unsigned short* WoT    = (unsigned short*)(ws + 33554432);   // [2048,2048] 8 MB
  unsigned short* q_lat  = (unsigned short*)(ws + 41943040);   // [4096,512]  4 MB
  unsigned short* kv_lat = (unsigned short*)(ws + 46137344);   // [4096,512]  4 MB
  unsigned short* qc     = (unsigned short*)(ws + 50331648);   // [4096,1024] 8 MB
  unsigned short* qp     = (unsigned short*)(ws + 58720256);   // [4096,1024] 8 MB
  unsigned short* kc     = (unsigned short*)(ws + 67108864);   // [4096,1024] 8 MB
  unsigned short* kp     = (unsigned short*)(ws + 75497472);   // [4096,1024] 8 MB
  unsigned short* vbuf   = (unsigned short*)(ws + 83886080);   // [4096,2048] 16 MB (reused as ao)
  unsigned short* qh     = (unsigned short*)(ws + 100663296);  // [B,H,T,128] 16 MB
  unsigned short* kh     = (unsigned short*)(ws + 117440512);  // 16 MB
  unsigned short* vt     = (unsigned short*)(ws + 134217728);  // [B,H,128,T] 16 MB
  unsigned short* ao     = vbuf; // alias: vbuf dead after vtrans

  dim3 tb(32, 8);

  cast_f32_bf16<<<(M_TOT * DM_ / 4 + 255) / 256, 256, 0, stream>>>(x, xb, M_TOT * DM_);

  transpose_cast<<<dim3(QR_/32, DM_/32), tb, 0, stream>>>(Wq_down, WqdT, DM_, QR_);
  transpose_cast<<<dim3((H_*CD_)/32, QR_/32), tb, 0, stream>>>(Wq_up, WquT, QR_, H_*CD_);
  transpose_cast<<<dim3((H_*RD_)/32, DM_/32), tb, 0, stream>>>(Wq_rope, WqrT, DM_, H_*RD_);
  transpose_cast<<<dim3(DL_/32, DM_/32), tb, 0, stream>>>(Wkv_down, WkvdT, DM_, DL_);
  transpose_cast<<<dim3((H_*CD_)/32, DL_/32), tb, 0, stream>>>(Wk_up, WkuT, DL_, H_*CD_);
  transpose_cast<<<dim3((H_*HD_)/32, DL_/32), tb, 0, stream>>>(Wv_up, WvuT, DL_, H_*HD_);
  transpose_cast<<<dim3((H_*RD_)/32, DM_/32), tb, 0, stream>>>(Wk_rope, WkrT, DM_, H_*RD_);
  transpose_cast<<<dim3(DM_/32, (H_*HD_)/32), tb, 0, stream>>>(Wo, WoT, H_*HD_, DM_);

  gemm_bt<0><<<dim3(QR_/128, M_TOT/128), 256, 0, stream>>>(xb, WqdT, q_lat, M_TOT, QR_, DM_);
  gemm_bt<0><<<dim3(DL_/128, M_TOT/128), 256, 0, stream>>>(xb, WkvdT, kv_lat, M_TOT, DL_, DM_);
  gemm_bt<0><<<dim3((H_*CD_)/128, M_TOT/128), 256, 0, stream>>>(q_lat, WquT, qc, M_TOT, H_*CD_, QR_);
  gemm_bt<0><<<dim3((H_*CD_)/128, M_TOT/128), 256, 0, stream>>>(kv_lat, WkuT, kc, M_TOT, H_*CD_, DL_);
  gemm_bt<0><<<dim3((H_*HD_)/128, M_TOT/128), 256, 0, stream>>>(kv_lat, WvuT, vbuf, M_TOT, H_*HD_, DL_);
  gemm_bt<0><<<dim3((H_*RD_)/128, M_TOT/128), 256, 0, stream>>>(xb, WqrT, qp, M_TOT, H_*RD_, DM_);
  gemm_bt<0><<<dim3((H_*RD_)/128, M_TOT/128), 256, 0, stream>>>(xb, WkrT, kp, M_TOT, H_*RD_, DM_);

  assemble_qk<<<dim3(B_*H_*T_/2), dim3(128, 2), 0, stream>>>(qc, qp, kc, kp, qh, kh);
  vtrans<<<dim3(T_/32, HD_/32, B_*H_), tb, 0, stream>>>(vbuf, vt);

  attn_fwd<<<dim3(T_/64, B_*H_), 256, 0, stream>>>(qh, kh, vt, ao);

  gemm_bt<1><<<dim3(DM_/128, M_TOT/128), 256, 0, stream>>>(ao, WoT, d_out, M_TOT, DM_, H_*HD_);
}

// Round 3
// 484.054 us; speedup vs baseline: 1.6536x; 1.6536x over previous
//
#include <hip/hip_runtime.h>
#include <stdint.h>
#include <math.h>

#define H_ 16
#define HD_ 128
#define RD_ 64
#define CD_ 64
#define DM_ 2048
#define QR_ 512
#define DL_ 512
#define B_ 2
#define T_ 2048
#define M_TOT (B_*T_)

typedef __attribute__((ext_vector_type(8))) short short8;
typedef __attribute__((ext_vector_type(4))) float f32x4;
typedef __attribute__((ext_vector_type(16))) float f32x16;

__device__ __forceinline__ unsigned short f2b(float f){
  union { float f; unsigned u; } a; a.f = f;
  unsigned r = a.u + 0x7fffu + ((a.u >> 16) & 1u);
  return (unsigned short)(r >> 16);
}
__device__ __forceinline__ float b2f(unsigned short b){
  union { unsigned u; float f; } a; a.u = ((unsigned)b) << 16;
  return a.f;
}

#define GLOAD16(g, l) __builtin_amdgcn_global_load_lds( \
    (__attribute__((address_space(1))) void*)(g), \
    (__attribute__((address_space(3))) void*)(l), 16, 0, 0)

// ---------------- cast f32 -> bf16 ----------------
__global__ void cast_f32_bf16(const float* __restrict__ src,
                              unsigned short* __restrict__ dst, int n){
  int i = (blockIdx.x * blockDim.x + threadIdx.x) * 4;
  if (i < n){
    float4 v = *(const float4*)(src + i);
    ushort4 o;
    o.x = f2b(v.x); o.y = f2b(v.y); o.z = f2b(v.z); o.w = f2b(v.w);
    *(ushort4*)(dst + i) = o;
  }
}

// ---------------- transpose + cast: W[K,N] f32 -> Wt[N,K] bf16 ----------------
__global__ void transpose_cast(const float* __restrict__ W,
                               unsigned short* __restrict__ Wt, int K, int N){
  __shared__ float tile[32][33];
  int n0 = blockIdx.x * 32, k0 = blockIdx.y * 32;
  int tx = threadIdx.x, ty = threadIdx.y; // (32,8)
  #pragma unroll
  for (int r = ty; r < 32; r += 8)
    tile[r][tx] = W[(size_t)(k0 + r) * N + n0 + tx];
  __syncthreads();
  #pragma unroll
  for (int r = ty; r < 32; r += 8)
    Wt[(size_t)(n0 + r) * K + k0 + tx] = f2b(tile[tx][r]);
}

// ---------------- GEMM: C[M,N] = A[M,K](bf16) @ Bt[N,K]^T (bf16) ----------------
template<int OUTF32>
__global__ __launch_bounds__(256) void gemm_bt(
    const unsigned short* __restrict__ A,
    const unsigned short* __restrict__ Bt,
    void* __restrict__ Cv, int M, int N, int K)
{
  __shared__ unsigned short As[128 * 32];
  __shared__ unsigned short Bs[128 * 32];
  int tid = threadIdx.x;
  int m0 = blockIdx.y * 128, n0 = blockIdx.x * 128;
  int lane = tid & 63, w = tid >> 6;
  int wr = (w >> 1) * 64, wc = (w & 1) * 64;
  int mr = lane & 15, kg = lane >> 4;

  const unsigned short* Ag = A  + (size_t)(m0 + (tid >> 2)) * K + ((tid & 3) << 3);
  const unsigned short* Bg = Bt + (size_t)(n0 + (tid >> 2)) * K + ((tid & 3) << 3);

  f32x4 acc[4][4];
  #pragma unroll
  for (int i = 0; i < 4; i++)
    #pragma unroll
    for (int j = 0; j < 4; j++)
      acc[i][j] = (f32x4){0.f, 0.f, 0.f, 0.f};

  for (int k0 = 0; k0 < K; k0 += 32) {
    #pragma unroll
    for (int j = 0; j < 2; j++) {
      GLOAD16(Ag + (size_t)j * 64 * K, &As[j * 2048 + tid * 8]);
      GLOAD16(Bg + (size_t)j * 64 * K, &Bs[j * 2048 + tid * 8]);
    }
    Ag += 32; Bg += 32;
    __syncthreads();
    short8 af[4], bf[4];
    #pragma unroll
    for (int i = 0; i < 4; i++)
      af[i] = *(const short8*)&As[(wr + i * 16 + mr) * 32 + kg * 8];
    #pragma unroll
    for (int j = 0; j < 4; j++)
      bf[j] = *(const short8*)&Bs[(wc + j * 16 + mr) * 32 + kg * 8];
    #pragma unroll
    for (int i = 0; i < 4; i++)
      #pragma unroll
      for (int j = 0; j < 4; j++)
        acc[i][j] = __builtin_amdgcn_mfma_f32_16x16x32_bf16(af[i], bf[j], acc[i][j], 0, 0, 0);
    __syncthreads();
  }

  if (OUTF32) {
    float* C = (float*)Cv;
    #pragma unroll
    for (int i = 0; i < 4; i++)
      #pragma unroll
      for (int j = 0; j < 4; j++)
        #pragma unroll
        for (int r = 0; r < 4; r++) {
          int row = m0 + wr + i * 16 + kg * 4 + r;
          int col = n0 + wc + j * 16 + mr;
          C[(size_t)row * N + col] = acc[i][j][r];
        }
  } else {
    unsigned short* C = (unsigned short*)Cv;
    #pragma unroll
    for (int i = 0; i < 4; i++)
      #pragma unroll
      for (int j = 0; j < 4; j++)
        #pragma unroll
        for (int r = 0; r < 4; r++) {
          int row = m0 + wr + i * 16 + kg * 4 + r;
          int col = n0 + wc + j * 16 + mr;
          C[(size_t)row * N + col] = f2b(acc[i][j][r]);
        }
  }
}

// ---------------- assemble q,k head-major with RoPE ----------------
__global__ void assemble_qk(const unsigned short* __restrict__ qc,
                            const unsigned short* __restrict__ qp,
                            const unsigned short* __restrict__ kc,
                            const unsigned short* __restrict__ kp,
                            unsigned short* __restrict__ qh,
                            unsigned short* __restrict__ kh){
  int row = blockIdx.x * 2 + threadIdx.y;   // (b,h,t) flattened
  int d = threadIdx.x;                      // 0..127
  int bh = row >> 11;                       // /T_
  int t  = row & (T_ - 1);
  int b = bh / H_, h = bh % H_;
  size_t srow = (size_t)b * T_ + t;
  size_t dst = ((size_t)bh * T_ + t) * 128 + d;
  if (d < 64) {
    qh[dst] = qc[srow * (H_*CD_) + h * 64 + d];
    kh[dst] = kc[srow * (H_*CD_) + h * 64 + d];
  } else {
    int i = d - 64;
    int j = i & 31;
    float invf = exp2f(-(float)j * 0.4152410118750f);
    float f = (float)t * invf;
    float s, c;
    sincosf(f, &s, &c);
    float qx1 = b2f(qp[srow * (H_*RD_) + h * 64 + j]);
    float qx2 = b2f(qp[srow * (H_*RD_) + h * 64 + j + 32]);
    float kx1 = b2f(kp[srow * (H_*RD_) + h * 64 + j]);
    float kx2 = b2f(kp[srow * (H_*RD_) + h * 64 + j + 32]);
    float qv = (i < 32) ? (qx1 * c - qx2 * s) : (qx1 * s + qx2 * c);
    float kv = (i < 32) ? (kx1 * c - kx2 * s) : (kx1 * s + kx2 * c);
    qh[dst] = f2b(qv);
    kh[dst] = f2b(kv);
  }
}

// ---------------- transpose v: [B*T, H*128] -> vt [B,H,128,T] ----------------
__global__ void vtrans(const unsigned short* __restrict__ vbuf,
                       unsigned short* __restrict__ vt){
  __shared__ unsigned short tile[32][33];
  int bh = blockIdx.z;
  int b = bh / H_, h = bh % H_;
  const unsigned short* src = vbuf + (size_t)b * T_ * (H_*HD_) + h * HD_;
  unsigned short* dst = vt + (size_t)bh * HD_ * T_;
  int t0 = blockIdx.x * 32, d0 = blockIdx.y * 32;
  int tx = threadIdx.x, ty = threadIdx.y; // (32,8)
  #pragma unroll
  for (int r = ty; r < 32; r += 8)
    tile[r][tx] = src[(size_t)(t0 + r) * (H_*HD_) + d0 + tx];
  __syncthreads();
  #pragma unroll
  for (int r = ty; r < 32; r += 8)
    dst[(size_t)(d0 + r) * T_ + t0 + tx] = tile[tx][r];
}

// ---------------- causal flash attention, 32x32 MFMA, 4 waves x 32 q-rows ----------------
// qh,kh: [B,H,T,128]; vt: [B,H,128,T]; ao: [B*T, H*128]
// Swapped QK^T (lane owns one q-row), K/V LDS-staged with XOR swizzle,
// 2-phase double-buffered pipeline.
__global__ __launch_bounds__(256) void attn_fwd2(
    const unsigned short* __restrict__ qh,
    const unsigned short* __restrict__ kh,
    const unsigned short* __restrict__ vt,
    unsigned short* __restrict__ ao)
{
  __shared__ __align__(16) unsigned short Ks[2][64 * 128];  // [kv][d] swizzled
  __shared__ __align__(16) unsigned short Vs[2][128 * 64];  // [d][kv] swizzled

  const int tid  = threadIdx.x;
  const int lane = tid & 63, w = tid >> 6;
  const int l31  = lane & 31, hi = lane >> 5;
  const int bh = blockIdx.y;
  const int b  = bh >> 4, hd = bh & 15;
  int qt = blockIdx.x;
  if (blockIdx.y >= 16) qt = 15 - qt;            // pair long+short tiles per CU
  const int q0    = qt * 128;
  const int q0w   = q0 + w * 32;
  const int qg    = q0w + l31;                   // this lane's q row
  const int qmaxw = q0w + 31;
  const int nt    = 2 * qt + 2;

  const unsigned short* Qg = qh + (size_t)bh * T_ * 128;
  const unsigned short* Kg = kh + (size_t)bh * T_ * 128;
  const unsigned short* Vg = vt + (size_t)bh * 128 * T_;

  // Q fragments: B-operand, col=q=l31, k = kc*16 + hi*8 + e
  short8 qf[8];
  #pragma unroll
  for (int kc = 0; kc < 8; kc++)
    qf[kc] = *(const short8*)&Qg[(size_t)qg * 128 + kc * 16 + hi * 8];

  f32x16 accO[4];
  #pragma unroll
  for (int sb = 0; sb < 4; sb++)
    #pragma unroll
    for (int r = 0; r < 16; r++) accO[sb][r] = 0.f;

  float m = -1e30f, lsum = 0.f;
  const float scale = 0.08838834764831845f;

  // staging: linear LDS dest + inverse-swizzled per-lane global source (rule 21)
#define STAGE_KV(bufi, kvt) do {                                              \
    int kv0s = (kvt) * 64;                                                    \
    _Pragma("unroll")                                                         \
    for (int j_ = 0; j_ < 4; j_++) {                                          \
      int ti = w * 4 + j_;                                                    \
      int r_ = ti * 4 + (lane >> 4);                                          \
      int cb = (lane & 15) * 16;                                              \
      int sz = cb ^ ((r_ & 7) << 4);                                          \
      GLOAD16(Kg + (size_t)(kv0s + r_) * 128 + (sz >> 1), &Ks[bufi][ti * 512]);\
    }                                                                         \
    _Pragma("unroll")                                                         \
    for (int j_ = 0; j_ < 4; j_++) {                                          \
      int ti = w * 4 + j_;                                                    \
      int d_ = ti * 8 + (lane >> 3);                                          \
      int cb = (lane & 7) * 16;                                               \
      int sz = cb ^ ((d_ & 7) << 4);                                          \
      GLOAD16(Vg + (size_t)d_ * T_ + kv0s + (sz >> 1), &Vs[bufi][ti * 512]);  \
    }                                                                         \
  } while (0)

  STAGE_KV(0, 0);
  int cur = 0;

  for (int t = 0; t < nt; t++) {
    __syncthreads();                       // drains vmcnt: buf[cur] ready
    if (t + 1 < nt) STAGE_KV(cur ^ 1, t + 1);
    const int kv0 = t * 64;
    if (kv0 <= qmaxw) {
      const unsigned short* Kb = &Ks[cur][0];
      const unsigned short* Vb = &Vs[cur][0];

      // ---- QK^T (swapped): S^T[kv][q], lane owns q col ----
      f32x16 sa0, sa1;
      #pragma unroll
      for (int r = 0; r < 16; r++) { sa0[r] = 0.f; sa1[r] = 0.f; }
      #pragma unroll
      for (int kc = 0; kc < 8; kc++) {
        int co = (kc * 32 + hi * 16);
        int r0 = l31;
        short8 kf0 = *(const short8*)&Kb[r0 * 128 + ((co ^ ((r0 & 7) << 4)) >> 1)];
        sa0 = __builtin_amdgcn_mfma_f32_32x32x16_bf16(kf0, qf[kc], sa0, 0, 0, 0);
        int r1 = 32 + l31;
        short8 kf1 = *(const short8*)&Kb[r1 * 128 + ((co ^ ((r1 & 7) << 4)) >> 1)];
        sa1 = __builtin_amdgcn_mfma_f32_32x32x16_bf16(kf1, qf[kc], sa1, 0, 0, 0);
      }

      // ---- lane-local softmax over 64 kv values ----
      float p0[16], p1[16];
      float pmax = -1e30f;
      bool needMask = (kv0 + 63 > q0w);   // mask iff tile can exceed ANY lane's q (min qg = q0w)
      if (needMask) {
        #pragma unroll
        for (int r = 0; r < 16; r++) {
          int crow = (r & 3) + 8 * (r >> 2) + 4 * hi;
          float v0 = sa0[r] * scale;
          float v1 = sa1[r] * scale;
          if (kv0 + crow > qg)      v0 = -1e30f;
          if (kv0 + 32 + crow > qg) v1 = -1e30f;
          p0[r] = v0; p1[r] = v1;
          pmax = fmaxf(pmax, fmaxf(v0, v1));
        }
      } else {
        #pragma unroll
        for (int r = 0; r < 16; r++) {
          float v0 = sa0[r] * scale;
          float v1 = sa1[r] * scale;
          p0[r] = v0; p1[r] = v1;
          pmax = fmaxf(pmax, fmaxf(v0, v1));
        }
      }
      pmax = fmaxf(pmax, __shfl_xor(pmax, 32, 64));
      float mn  = fmaxf(m, pmax);
      float fac = __expf(m - mn);
      m = mn;
      float ls = 0.f;
      #pragma unroll
      for (int r = 0; r < 16; r++) {
        p0[r] = __expf(p0[r] - mn);
        p1[r] = __expf(p1[r] - mn);
        ls += p0[r] + p1[r];
      }
      ls += __shfl_xor(ls, 32, 64);
      lsum = lsum * fac + ls;
      #pragma unroll
      for (int sb = 0; sb < 4; sb++)
        #pragma unroll
        for (int r = 0; r < 16; r++) accO[sb][r] *= fac;

      // ---- PV: O^T[d][q] += V^T-frag x P-frag ----
      #pragma unroll
      for (int kc2 = 0; kc2 < 4; kc2++) {
        const int c2 = kc2 & 1;
        short8 pa;
        #pragma unroll
        for (int j = 0; j < 4; j++) {
          float a  = (kc2 < 2) ? p0[8 * c2 + j]     : p1[8 * c2 + j];
          float bv = (kc2 < 2) ? p0[8 * c2 + 4 + j] : p1[8 * c2 + 4 + j];
          float snd = hi ? a : bv;
          float rcv = __shfl_xor(snd, 32, 64);
          float lo = hi ? rcv : a;
          float hh = hi ? bv : rcv;
          pa[j]     = (short)f2b(lo);
          pa[4 + j] = (short)f2b(hh);
        }
        #pragma unroll
        for (int sb = 0; sb < 4; sb++) {
          int d = sb * 32 + l31;
          short8 vf = *(const short8*)&Vb[d * 64 + (((kc2 * 32 + hi * 16) ^ ((d & 7) << 4)) >> 1)];
          accO[sb] = __builtin_amdgcn_mfma_f32_32x32x16_bf16(vf, pa, accO[sb], 0, 0, 0);
        }
      }
    }
    cur ^= 1;
  }

  float rl = 1.0f / lsum;
  size_t orow = ((size_t)b * T_ + qg) * (H_*HD_) + hd * 128;
  #pragma unroll
  for (int sb = 0; sb < 4; sb++)
    #pragma unroll
    for (int g = 0; g < 4; g++) {
      ushort4 o;
      o.x = f2b(accO[sb][4 * g + 0] * rl);
      o.y = f2b(accO[sb][4 * g + 1] * rl);
      o.z = f2b(accO[sb][4 * g + 2] * rl);
      o.w = f2b(accO[sb][4 * g + 3] * rl);
      *(ushort4*)&ao[orow + sb * 32 + 8 * g + 4 * hi] = o;
    }
#undef STAGE_KV
}

// ---------------- launcher ----------------
extern "C" void kernel_launch(void* const* d_in, const int* in_sizes, int n_in,
                              void* d_out, int out_size, void* d_ws, size_t ws_size,
                              hipStream_t stream)
{
  (void)in_sizes; (void)n_in; (void)out_size; (void)ws_size;
  const float* x        = (const float*)d_in[0];
  const float* Wq_down  = (const float*)d_in[1];
  const float* Wq_up    = (const float*)d_in[2];
  const float* Wq_rope  = (const float*)d_in[3];
  const float* Wkv_down = (const float*)d_in[4];
  const float* Wk_up    = (const float*)d_in[5];
  const float* Wv_up    = (const float*)d_in[6];
  const float* Wk_rope  = (const float*)d_in[7];
  const float* Wo       = (const float*)d_in[8];

  char* ws = (char*)d_ws;
  unsigned short* xb     = (unsigned short*)(ws + 0);          // 16 MB
  unsigned short* WqdT   = (unsigned short*)(ws + 16777216);
  unsigned short* WquT   = (unsigned short*)(ws + 18874368);
  unsigned short* WqrT   = (unsigned short*)(ws + 19922944);
  unsigned short* WkvdT  = (unsigned short*)(ws + 24117248);
  unsigned short* WkuT   = (unsigned short*)(ws + 26214400);
  unsigned short* WvuT   = (unsigned short*)(ws + 27262976);
  unsigned short* WkrT   = (unsigned short*)(ws + 29360128);
  unsigned short* WoT    = (unsigned short*)(ws + 33554432);
  unsigned short* q_lat  = (unsigned short*)(ws + 41943040);
  unsigned short* kv_lat = (unsigned short*)(ws + 46137344);
  unsigned short* qc     = (unsigned short*)(ws + 50331648);
  unsigned short* qp     = (unsigned short*)(ws + 58720256);
  unsigned short* kc     = (unsigned short*)(ws + 67108864);
  unsigned short* kp     = (unsigned short*)(ws + 75497472);
  unsigned short* vbuf   = (unsigned short*)(ws + 83886080);   // reused as ao
  unsigned short* qh     = (unsigned short*)(ws + 100663296);
  unsigned short* kh     = (unsigned short*)(ws + 117440512);
  unsigned short* vt     = (unsigned short*)(ws + 134217728);
  unsigned short* ao     = vbuf;

  dim3 tb(32, 8);

  cast_f32_bf16<<<(M_TOT * DM_ / 4 + 255) / 256, 256, 0, stream>>>(x, xb, M_TOT * DM_);

  transpose_cast<<<dim3(QR_/32, DM_/32), tb, 0, stream>>>(Wq_down, WqdT, DM_, QR_);
  transpose_cast<<<dim3((H_*CD_)/32, QR_/32), tb, 0, stream>>>(Wq_up, WquT, QR_, H_*CD_);
  transpose_cast<<<dim3((H_*RD_)/32, DM_/32), tb, 0, stream>>>(Wq_rope, WqrT, DM_, H_*RD_);
  transpose_cast<<<dim3(DL_/32, DM_/32), tb, 0, stream>>>(Wkv_down, WkvdT, DM_, DL_);
  transpose_cast<<<dim3((H_*CD_)/32, DL_/32), tb, 0, stream>>>(Wk_up, WkuT, DL_, H_*CD_);
  transpose_cast<<<dim3((H_*HD_)/32, DL_/32), tb, 0, stream>>>(Wv_up, WvuT, DL_, H_*HD_);
  transpose_cast<<<dim3((H_*RD_)/32, DM_/32), tb, 0, stream>>>(Wk_rope, WkrT, DM_, H_*RD_);
  transpose_cast<<<dim3(DM_/32, (H_*HD_)/32), tb, 0, stream>>>(Wo, WoT, H_*HD_, DM_);

  gemm_bt<0><<<dim3(QR_/128, M_TOT/128), 256, 0, stream>>>(xb, WqdT, q_lat, M_TOT, QR_, DM_);
  gemm_bt<0><<<dim3(DL_/128, M_TOT/128), 256, 0, stream>>>(xb, WkvdT, kv_lat, M_TOT, DL_, DM_);
  gemm_bt<0><<<dim3((H_*CD_)/128, M_TOT/128), 256, 0, stream>>>(q_lat, WquT, qc, M_TOT, H_*CD_, QR_);
  gemm_bt<0><<<dim3((H_*CD_)/128, M_TOT/128), 256, 0, stream>>>(kv_lat, WkuT, kc, M_TOT, H_*CD_, DL_);
  gemm_bt<0><<<dim3((H_*HD_)/128, M_TOT/128), 256, 0, stream>>>(kv_lat, WvuT, vbuf, M_TOT, H_*HD_, DL_);
  gemm_bt<0><<<dim3((H_*RD_)/128, M_TOT/128), 256, 0, stream>>>(xb, WqrT, qp, M_TOT, H_*RD_, DM_);
  gemm_bt<0><<<dim3((H_*RD_)/128, M_TOT/128), 256, 0, stream>>>(xb, WkrT, kp, M_TOT, H_*RD_, DM_);

  assemble_qk<<<dim3(B_*H_*T_/2), dim3(128, 2), 0, stream>>>(qc, qp, kc, kp, qh, kh);
  vtrans<<<dim3(T_/32, HD_/32, B_*H_), tb, 0, stream>>>(vbuf, vt);

  attn_fwd2<<<dim3(16, 32), 256, 0, stream>>>(qh, kh, vt, ao);

  gemm_bt<1><<<dim3(DM_/128, M_TOT/128), 256, 0, stream>>>(ao, WoT, d_out, M_TOT, DM_, H_*HD_);
}

// Round 4
// 386.959 us; speedup vs baseline: 2.0685x; 1.2509x over previous
//
#include <hip/hip_runtime.h>
#include <hip/hip_bf16.h>
#include <stdint.h>
#include <math.h>

#define H_ 16
#define HD_ 128
#define RD_ 64
#define CD_ 64
#define DM_ 2048
#define QR_ 512
#define DL_ 512
#define B_ 2
#define T_ 2048
#define M_TOT (B_*T_)

typedef __attribute__((ext_vector_type(8))) short short8;
typedef __attribute__((ext_vector_type(4))) float f32x4;
typedef __attribute__((ext_vector_type(16))) float f32x16;

__device__ __forceinline__ unsigned short f2b_hw(float f){
  __hip_bfloat16 h = __float2bfloat16(f);
  union { __hip_bfloat16 h; unsigned short u; } c; c.h = h; return c.u;
}
__device__ __forceinline__ float b2f(unsigned short b){
  union { unsigned u; float f; } a; a.u = ((unsigned)b) << 16;
  return a.f;
}

#define GLOAD16(g, l) __builtin_amdgcn_global_load_lds( \
    (__attribute__((address_space(1))) void*)(g), \
    (__attribute__((address_space(3))) void*)(l), 16, 0, 0)

// ---------------- cast f32 -> bf16 ----------------
__global__ void cast_f32_bf16(const float* __restrict__ src,
                              unsigned short* __restrict__ dst, int n){
  int i = (blockIdx.x * blockDim.x + threadIdx.x) * 4;
  if (i < n){
    float4 v = *(const float4*)(src + i);
    ushort4 o;
    o.x = f2b_hw(v.x); o.y = f2b_hw(v.y); o.z = f2b_hw(v.z); o.w = f2b_hw(v.w);
    *(ushort4*)(dst + i) = o;
  }
}

// ---------------- combined transpose+cast for all 8 weights ----------------
struct TTe { const float* src; unsigned short* dst; int K, N, blk0; };
struct TT8 { TTe e[8]; };

__global__ void transpose_cast8(TT8 tab){
  __shared__ float tile[32][33];
  int bid = blockIdx.x;
  const float* src = tab.e[0].src;
  unsigned short* dst = tab.e[0].dst;
  int K = tab.e[0].K, N = tab.e[0].N, loc = bid;
  #pragma unroll
  for (int j = 1; j < 8; j++){
    if (bid >= tab.e[j].blk0){
      src = tab.e[j].src; dst = tab.e[j].dst;
      K = tab.e[j].K; N = tab.e[j].N; loc = bid - tab.e[j].blk0;
    }
  }
  int cols = N / 32;
  int n0 = (loc % cols) * 32, k0 = (loc / cols) * 32;
  int tx = threadIdx.x, ty = threadIdx.y; // (32,8)
  #pragma unroll
  for (int r = ty; r < 32; r += 8)
    tile[r][tx] = src[(size_t)(k0 + r) * N + n0 + tx];
  __syncthreads();
  #pragma unroll
  for (int r = ty; r < 32; r += 8)
    dst[(size_t)(n0 + r) * K + k0 + tx] = f2b_hw(tile[tx][r]);
}

// ---------------- GEMM: C[M,:] = A[M,K](bf16, row-stride lda) @ Bt[N,K]^T ----------------
// m97 structure: 128x128 tile, BK=32, 4 waves, global_load_lds w16, XCD swizzle.
template<int OUTF32>
__global__ __launch_bounds__(256) void gemm_bt(
    const unsigned short* __restrict__ A, int lda,
    const unsigned short* __restrict__ Bt,
    void* __restrict__ Cv, int ldc, int N, int K)
{
  __shared__ unsigned short As[128 * 32];
  __shared__ unsigned short Bs[128 * 32];
  int tid = threadIdx.x;

  // bijective XCD swizzle (nwg % 8 == 0 for all launches)
  int gx = gridDim.x;
  int nwg = gx * gridDim.y;
  int lin = blockIdx.x + gx * blockIdx.y;
  int q8 = nwg >> 3;
  int nl = (lin & 7) * q8 + (lin >> 3);
  int m0 = (nl / gx) * 128, n0 = (nl % gx) * 128;

  int lane = tid & 63, w = tid >> 6;
  int wr = (w >> 1) * 64, wc = (w & 1) * 64;
  int mr = lane & 15, kg = lane >> 4;

  const unsigned short* Ag = A  + (size_t)(m0 + (tid >> 2)) * lda + ((tid & 3) << 3);
  const unsigned short* Bg = Bt + (size_t)(n0 + (tid >> 2)) * K + ((tid & 3) << 3);

  f32x4 acc[4][4];
  #pragma unroll
  for (int i = 0; i < 4; i++)
    #pragma unroll
    for (int j = 0; j < 4; j++)
      acc[i][j] = (f32x4){0.f, 0.f, 0.f, 0.f};

  for (int k0 = 0; k0 < K; k0 += 32) {
    #pragma unroll
    for (int j = 0; j < 2; j++) {
      GLOAD16(Ag + (size_t)j * 64 * lda, &As[j * 2048 + tid * 8]);
      GLOAD16(Bg + (size_t)j * 64 * K, &Bs[j * 2048 + tid * 8]);
    }
    Ag += 32; Bg += 32;
    __syncthreads();
    short8 af[4], bf[4];
    #pragma unroll
    for (int i = 0; i < 4; i++)
      af[i] = *(const short8*)&As[(wr + i * 16 + mr) * 32 + kg * 8];
    #pragma unroll
    for (int j = 0; j < 4; j++)
      bf[j] = *(const short8*)&Bs[(wc + j * 16 + mr) * 32 + kg * 8];
    __builtin_amdgcn_s_setprio(1);
    #pragma unroll
    for (int i = 0; i < 4; i++)
      #pragma unroll
      for (int j = 0; j < 4; j++)
        acc[i][j] = __builtin_amdgcn_mfma_f32_16x16x32_bf16(af[i], bf[j], acc[i][j], 0, 0, 0);
    __builtin_amdgcn_s_setprio(0);
    __syncthreads();
  }

  if (OUTF32) {
    float* C = (float*)Cv;
    #pragma unroll
    for (int i = 0; i < 4; i++)
      #pragma unroll
      for (int j = 0; j < 4; j++)
        #pragma unroll
        for (int r = 0; r < 4; r++) {
          int row = m0 + wr + i * 16 + kg * 4 + r;
          int col = n0 + wc + j * 16 + mr;
          C[(size_t)row * ldc + col] = acc[i][j][r];
        }
  } else {
    unsigned short* C = (unsigned short*)Cv;
    #pragma unroll
    for (int i = 0; i < 4; i++)
      #pragma unroll
      for (int j = 0; j < 4; j++)
        #pragma unroll
        for (int r = 0; r < 4; r++) {
          int row = m0 + wr + i * 16 + kg * 4 + r;
          int col = n0 + wc + j * 16 + mr;
          C[(size_t)row * ldc + col] = f2b_hw(acc[i][j][r]);
        }
  }
}

// ---------------- assemble q,k head-major with RoPE ----------------
// qc:[4096,1024] ld 1024 | qp: rope+0 ld 2048 | kc: kcv+0 ld 3072 | kp: rope+1024 ld 2048
__global__ void assemble_qk(const unsigned short* __restrict__ qc,
                            const unsigned short* __restrict__ rope,
                            const unsigned short* __restrict__ kcv,
                            unsigned short* __restrict__ qh,
                            unsigned short* __restrict__ kh){
  int row = blockIdx.x * 2 + threadIdx.y;   // (b,h,t) flattened
  int d = threadIdx.x;                      // 0..127
  int bh = row >> 11;                       // /T_
  int t  = row & (T_ - 1);
  int b = bh / H_, h = bh % H_;
  size_t srow = (size_t)b * T_ + t;
  size_t dst = ((size_t)bh * T_ + t) * 128 + d;
  if (d < 64) {
    qh[dst] = qc[srow * 1024 + h * 64 + d];
    kh[dst] = kcv[srow * 3072 + h * 64 + d];
  } else {
    int i = d - 64;
    int j = i & 31;
    float invf = exp2f(-(float)j * 0.4152410118750f);
    float f = (float)t * invf;
    float s, c;
    sincosf(f, &s, &c);
    float qx1 = b2f(rope[srow * 2048 + h * 64 + j]);
    float qx2 = b2f(rope[srow * 2048 + h * 64 + j + 32]);
    float kx1 = b2f(rope[srow * 2048 + 1024 + h * 64 + j]);
    float kx2 = b2f(rope[srow * 2048 + 1024 + h * 64 + j + 32]);
    float qv = (i < 32) ? (qx1 * c - qx2 * s) : (qx1 * s + qx2 * c);
    float kv = (i < 32) ? (kx1 * c - kx2 * s) : (kx1 * s + kx2 * c);
    qh[dst] = f2b_hw(qv);
    kh[dst] = f2b_hw(kv);
  }
}

// ---------------- transpose v: kcv cols [1024:3072] -> vt [B,H,128,T] ----------------
__global__ void vtrans(const unsigned short* __restrict__ kcv,
                       unsigned short* __restrict__ vt){
  __shared__ unsigned short tile[32][33];
  int bh = blockIdx.z;
  int b = bh / H_, h = bh % H_;
  const unsigned short* src = kcv + (size_t)b * T_ * 3072 + 1024 + h * HD_;
  unsigned short* dst = vt + (size_t)bh * HD_ * T_;
  int t0 = blockIdx.x * 32, d0 = blockIdx.y * 32;
  int tx = threadIdx.x, ty = threadIdx.y; // (32,8)
  #pragma unroll
  for (int r = ty; r < 32; r += 8)
    tile[r][tx] = src[(size_t)(t0 + r) * 3072 + d0 + tx];
  __syncthreads();
  #pragma unroll
  for (int r = ty; r < 32; r += 8)
    dst[(size_t)(d0 + r) * T_ + t0 + tx] = tile[tx][r];
}

// ---------------- causal flash attention, 32x32 MFMA, 4 waves x 32 q-rows ----------------
__global__ __launch_bounds__(256) void attn_fwd2(
    const unsigned short* __restrict__ qh,
    const unsigned short* __restrict__ kh,
    const unsigned short* __restrict__ vt,
    unsigned short* __restrict__ ao)
{
  __shared__ __align__(16) unsigned short Ks[2][64 * 128];  // [kv][d] swizzled
  __shared__ __align__(16) unsigned short Vs[2][128 * 64];  // [d][kv] swizzled

  const int tid  = threadIdx.x;
  const int lane = tid & 63, w = tid >> 6;
  const int l31  = lane & 31, hi = lane >> 5;
  const int bh = blockIdx.y;
  const int b  = bh >> 4, hd = bh & 15;
  int qt = blockIdx.x;
  if (blockIdx.y >= 16) qt = 15 - qt;            // pair long+short tiles per CU
  const int q0    = qt * 128;
  const int q0w   = q0 + w * 32;
  const int qg    = q0w + l31;
  const int qmaxw = q0w + 31;
  const int nt    = 2 * qt + 2;

  const unsigned short* Qg = qh + (size_t)bh * T_ * 128;
  const unsigned short* Kg = kh + (size_t)bh * T_ * 128;
  const unsigned short* Vg = vt + (size_t)bh * 128 * T_;

  short8 qf[8];
  #pragma unroll
  for (int kc = 0; kc < 8; kc++)
    qf[kc] = *(const short8*)&Qg[(size_t)qg * 128 + kc * 16 + hi * 8];

  f32x16 accO[4];
  #pragma unroll
  for (int sb = 0; sb < 4; sb++)
    #pragma unroll
    for (int r = 0; r < 16; r++) accO[sb][r] = 0.f;

  // softmax in exp2 domain: scores pre-multiplied by scale*log2(e)
  float m = -1e30f, lsum = 0.f;
  const float SC = 0.12751743f;   // (1/sqrt(128)) * log2(e)

#define STAGE_KV(bufi, kvt) do {                                              \
    int kv0s = (kvt) * 64;                                                    \
    _Pragma("unroll")                                                         \
    for (int j_ = 0; j_ < 4; j_++) {                                          \
      int ti = w * 4 + j_;                                                    \
      int r_ = ti * 4 + (lane >> 4);                                          \
      int cb = (lane & 15) * 16;                                              \
      int sz = cb ^ ((r_ & 7) << 4);                                          \
      GLOAD16(Kg + (size_t)(kv0s + r_) * 128 + (sz >> 1), &Ks[bufi][ti * 512]);\
    }                                                                         \
    _Pragma("unroll")                                                         \
    for (int j_ = 0; j_ < 4; j_++) {                                          \
      int ti = w * 4 + j_;                                                    \
      int d_ = ti * 8 + (lane >> 3);                                          \
      int cb = (lane & 7) * 16;                                               \
      int sz = cb ^ ((d_ & 7) << 4);                                          \
      GLOAD16(Vg + (size_t)d_ * T_ + kv0s + (sz >> 1), &Vs[bufi][ti * 512]);  \
    }                                                                         \
  } while (0)

  STAGE_KV(0, 0);
  int cur = 0;

  for (int t = 0; t < nt; t++) {
    __syncthreads();
    if (t + 1 < nt) STAGE_KV(cur ^ 1, t + 1);
    const int kv0 = t * 64;
    if (kv0 <= qmaxw) {
      const unsigned short* Kb = &Ks[cur][0];
      const unsigned short* Vb = &Vs[cur][0];

      // ---- QK^T (swapped): S^T[kv][q], lane owns q col ----
      f32x16 sa0, sa1;
      #pragma unroll
      for (int r = 0; r < 16; r++) { sa0[r] = 0.f; sa1[r] = 0.f; }
      __builtin_amdgcn_s_setprio(1);
      #pragma unroll
      for (int kc = 0; kc < 8; kc++) {
        int co = (kc * 32 + hi * 16);
        int r0 = l31;
        short8 kf0 = *(const short8*)&Kb[r0 * 128 + ((co ^ ((r0 & 7) << 4)) >> 1)];
        sa0 = __builtin_amdgcn_mfma_f32_32x32x16_bf16(kf0, qf[kc], sa0, 0, 0, 0);
        int r1 = 32 + l31;
        short8 kf1 = *(const short8*)&Kb[r1 * 128 + ((co ^ ((r1 & 7) << 4)) >> 1)];
        sa1 = __builtin_amdgcn_mfma_f32_32x32x16_bf16(kf1, qf[kc], sa1, 0, 0, 0);
      }
      __builtin_amdgcn_s_setprio(0);

      // ---- lane-local softmax (exp2 domain) ----
      float p0[16], p1[16];
      float pmax = -1e30f;
      bool needMask = (kv0 + 63 > q0w);
      if (needMask) {
        #pragma unroll
        for (int r = 0; r < 16; r++) {
          int crow = (r & 3) + 8 * (r >> 2) + 4 * hi;
          float v0 = sa0[r] * SC;
          float v1 = sa1[r] * SC;
          if (kv0 + crow > qg)      v0 = -1e30f;
          if (kv0 + 32 + crow > qg) v1 = -1e30f;
          p0[r] = v0; p1[r] = v1;
          pmax = fmaxf(pmax, fmaxf(v0, v1));
        }
      } else {
        #pragma unroll
        for (int r = 0; r < 16; r++) {
          float v0 = sa0[r] * SC;
          float v1 = sa1[r] * SC;
          p0[r] = v0; p1[r] = v1;
          pmax = fmaxf(pmax, fmaxf(v0, v1));
        }
      }
      pmax = fmaxf(pmax, __shfl_xor(pmax, 32, 64));
      // T13 defer-max: skip rescale when max growth small (P bounded by 2^8)
      if (!__all(pmax <= m + 8.f)) {
        float mn  = fmaxf(m, pmax);
        float fac = exp2f(m - mn);
        m = mn;
        lsum *= fac;
        #pragma unroll
        for (int sb = 0; sb < 4; sb++)
          #pragma unroll
          for (int r = 0; r < 16; r++) accO[sb][r] *= fac;
      }
      float ls = 0.f;
      #pragma unroll
      for (int r = 0; r < 16; r++) {
        p0[r] = exp2f(p0[r] - m);
        p1[r] = exp2f(p1[r] - m);
        ls += p0[r] + p1[r];
      }
      ls += __shfl_xor(ls, 32, 64);
      lsum += ls;

      // ---- PV: O^T[d][q] += V^T-frag x P-frag ----
      #pragma unroll
      for (int kc2 = 0; kc2 < 4; kc2++) {
        const int c2 = kc2 & 1;
        short8 pa;
        #pragma unroll
        for (int j = 0; j < 4; j++) {
          float a  = (kc2 < 2) ? p0[8 * c2 + j]     : p1[8 * c2 + j];
          float bv = (kc2 < 2) ? p0[8 * c2 + 4 + j] : p1[8 * c2 + 4 + j];
          float snd = hi ? a : bv;
          float rcv = __shfl_xor(snd, 32, 64);
          float lo = hi ? rcv : a;
          float hh = hi ? bv : rcv;
          pa[j]     = (short)f2b_hw(lo);
          pa[4 + j] = (short)f2b_hw(hh);
        }
        __builtin_amdgcn_s_setprio(1);
        #pragma unroll
        for (int sb = 0; sb < 4; sb++) {
          int d = sb * 32 + l31;
          short8 vf = *(const short8*)&Vb[d * 64 + (((kc2 * 32 + hi * 16) ^ ((d & 7) << 4)) >> 1)];
          accO[sb] = __builtin_amdgcn_mfma_f32_32x32x16_bf16(vf, pa, accO[sb], 0, 0, 0);
        }
        __builtin_amdgcn_s_setprio(0);
      }
    }
    cur ^= 1;
  }

  float rl = 1.0f / lsum;
  size_t orow = ((size_t)b * T_ + qg) * (H_*HD_) + hd * 128;
  #pragma unroll
  for (int sb = 0; sb < 4; sb++)
    #pragma unroll
    for (int g = 0; g < 4; g++) {
      ushort4 o;
      o.x = f2b_hw(accO[sb][4 * g + 0] * rl);
      o.y = f2b_hw(accO[sb][4 * g + 1] * rl);
      o.z = f2b_hw(accO[sb][4 * g + 2] * rl);
      o.w = f2b_hw(accO[sb][4 * g + 3] * rl);
      *(ushort4*)&ao[orow + sb * 32 + 8 * g + 4 * hi] = o;
    }
#undef STAGE_KV
}

// ---------------- launcher ----------------
extern "C" void kernel_launch(void* const* d_in, const int* in_sizes, int n_in,
                              void* d_out, int out_size, void* d_ws, size_t ws_size,
                              hipStream_t stream)
{
  (void)in_sizes; (void)n_in; (void)out_size; (void)ws_size;
  const float* x        = (const float*)d_in[0];
  const float* Wq_down  = (const float*)d_in[1];
  const float* Wq_up    = (const float*)d_in[2];
  const float* Wq_rope  = (const float*)d_in[3];
  const float* Wkv_down = (const float*)d_in[4];
  const float* Wk_up    = (const float*)d_in[5];
  const float* Wv_up    = (const float*)d_in[6];
  const float* Wk_rope  = (const float*)d_in[7];
  const float* Wo       = (const float*)d_in[8];

  char* ws = (char*)d_ws;
  unsigned short* xb     = (unsigned short*)(ws + 0);          // [4096,2048] 16 MB
  unsigned short* WdLat  = (unsigned short*)(ws + 16777216);   // [1024,2048] 4 MB (Wq_down^T | Wkv_down^T)
  unsigned short* WdRope = (unsigned short*)(ws + 20971520);   // [2048,2048] 8 MB (Wq_rope^T | Wk_rope^T)
  unsigned short* WquT   = (unsigned short*)(ws + 29360128);   // [1024,512]  1 MB
  unsigned short* WkcvT  = (unsigned short*)(ws + 30408704);   // [3072,512]  3 MB (Wk_up^T | Wv_up^T)
  unsigned short* WoT    = (unsigned short*)(ws + 33554432);   // [2048,2048] 8 MB
  unsigned short* latbuf = (unsigned short*)(ws + 41943040);   // [4096,1024] 8 MB (q_lat | kv_lat)
  unsigned short* ropebf = (unsigned short*)(ws + 50331648);   // [4096,2048] 16 MB (qp | kp); reused as ao
  unsigned short* qcbuf  = (unsigned short*)(ws + 67108864);   // [4096,1024] 8 MB
  unsigned short* kcvbuf = (unsigned short*)(ws + 75497472);   // [4096,3072] 24 MB (kc | v)
  unsigned short* qh     = (unsigned short*)(ws + 100663296);  // [B,H,T,128] 16 MB
  unsigned short* kh     = (unsigned short*)(ws + 117440512);  // 16 MB
  unsigned short* vt     = (unsigned short*)(ws + 134217728);  // [B,H,128,T] 16 MB
  unsigned short* ao     = ropebf;  // ropebf dead after assemble_qk

  dim3 tb(32, 8);

  cast_f32_bf16<<<(M_TOT * DM_ / 4 + 255) / 256, 256, 0, stream>>>(x, xb, M_TOT * DM_);

  // all 8 weight transposes in one launch
  TT8 tab;
  int blk = 0;
  tab.e[0] = { Wq_down,  WdLat,               DM_, QR_,     blk }; blk += (QR_/32)*(DM_/32);      // 1024
  tab.e[1] = { Wkv_down, WdLat + 512*2048,    DM_, DL_,     blk }; blk += (DL_/32)*(DM_/32);      // 1024
  tab.e[2] = { Wq_rope,  WdRope,              DM_, H_*RD_,  blk }; blk += (H_*RD_/32)*(DM_/32);   // 2048
  tab.e[3] = { Wk_rope,  WdRope + 1024*2048,  DM_, H_*RD_,  blk }; blk += (H_*RD_/32)*(DM_/32);   // 2048
  tab.e[4] = { Wq_up,    WquT,                QR_, H_*CD_,  blk }; blk += (H_*CD_/32)*(QR_/32);   // 512
  tab.e[5] = { Wk_up,    WkcvT,               DL_, H_*CD_,  blk }; blk += (H_*CD_/32)*(DL_/32);   // 512
  tab.e[6] = { Wv_up,    WkcvT + 1024*512,    DL_, H_*HD_,  blk }; blk += (H_*HD_/32)*(DL_/32);   // 1024
  tab.e[7] = { Wo,       WoT,                 H_*HD_, DM_,  blk }; blk += (DM_/32)*(H_*HD_/32);   // 4096
  transpose_cast8<<<blk, tb, 0, stream>>>(tab);

  // fused projections
  gemm_bt<0><<<dim3(1024/128, M_TOT/128), 256, 0, stream>>>(xb, DM_, WdLat, latbuf, 1024, 1024, DM_);
  gemm_bt<0><<<dim3(2048/128, M_TOT/128), 256, 0, stream>>>(xb, DM_, WdRope, ropebf, 2048, 2048, DM_);
  gemm_bt<0><<<dim3(1024/128, M_TOT/128), 256, 0, stream>>>(latbuf, 1024, WquT, qcbuf, 1024, 1024, QR_);
  gemm_bt<0><<<dim3(3072/128, M_TOT/128), 256, 0, stream>>>(latbuf + 512, 1024, WkcvT, kcvbuf, 3072, 3072, DL_);

  assemble_qk<<<dim3(B_*H_*T_/2), dim3(128, 2), 0, stream>>>(qcbuf, ropebf, kcvbuf, qh, kh);
  vtrans<<<dim3(T_/32, HD_/32, B_*H_), tb, 0, stream>>>(kcvbuf, vt);

  attn_fwd2<<<dim3(16, 32), 256, 0, stream>>>(qh, kh, vt, ao);

  gemm_bt<1><<<dim3(DM_/128, M_TOT/128), 256, 0, stream>>>(ao, 2048, WoT, d_out, DM_, DM_, H_*HD_);
}

// Round 5
// 350.619 us; speedup vs baseline: 2.2829x; 1.1036x over previous
//
#include <hip/hip_runtime.h>
#include <hip/hip_bf16.h>
#include <stdint.h>
#include <math.h>

#define H_ 16
#define HD_ 128
#define RD_ 64
#define CD_ 64
#define DM_ 2048
#define QR_ 512
#define DL_ 512
#define B_ 2
#define T_ 2048
#define M_TOT (B_*T_)

typedef __attribute__((ext_vector_type(8))) short short8;
typedef __attribute__((ext_vector_type(4))) float f32x4;
typedef __attribute__((ext_vector_type(16))) float f32x16;

__device__ __forceinline__ unsigned short f2b_hw(float f){
  __hip_bfloat16 h = __float2bfloat16(f);
  union { __hip_bfloat16 h; unsigned short u; } c; c.h = h; return c.u;
}
__device__ __forceinline__ float b2f(unsigned short b){
  union { unsigned u; float f; } a; a.u = ((unsigned)b) << 16;
  return a.f;
}

#define GLOAD16(g, l) __builtin_amdgcn_global_load_lds( \
    (__attribute__((address_space(1))) void*)(g), \
    (__attribute__((address_space(3))) void*)(l), 16, 0, 0)

// ---------------- cast f32 -> bf16 ----------------
__global__ void cast_f32_bf16(const float* __restrict__ src,
                              unsigned short* __restrict__ dst, int n){
  int i = (blockIdx.x * blockDim.x + threadIdx.x) * 4;
  if (i < n){
    float4 v = *(const float4*)(src + i);
    ushort4 o;
    o.x = f2b_hw(v.x); o.y = f2b_hw(v.y); o.z = f2b_hw(v.z); o.w = f2b_hw(v.w);
    *(ushort4*)(dst + i) = o;
  }
}

// ---------------- combined transpose+cast for all 8 weights ----------------
struct TTe { const float* src; unsigned short* dst; int K, N, blk0; };
struct TT8 { TTe e[8]; };

__global__ void transpose_cast8(TT8 tab){
  __shared__ float tile[32][33];
  int bid = blockIdx.x;
  const float* src = tab.e[0].src;
  unsigned short* dst = tab.e[0].dst;
  int K = tab.e[0].K, N = tab.e[0].N, loc = bid;
  #pragma unroll
  for (int j = 1; j < 8; j++){
    if (bid >= tab.e[j].blk0){
      src = tab.e[j].src; dst = tab.e[j].dst;
      K = tab.e[j].K; N = tab.e[j].N; loc = bid - tab.e[j].blk0;
    }
  }
  int cols = N / 32;
  int n0 = (loc % cols) * 32, k0 = (loc / cols) * 32;
  int tx = threadIdx.x, ty = threadIdx.y; // (32,8)
  #pragma unroll
  for (int r = ty; r < 32; r += 8)
    tile[r][tx] = src[(size_t)(k0 + r) * N + n0 + tx];
  __syncthreads();
  #pragma unroll
  for (int r = ty; r < 32; r += 8)
    dst[(size_t)(n0 + r) * K + k0 + tx] = f2b_hw(tile[tx][r]);
}

// ---------------- GEMM: C[M,:] = A[M,K](bf16, row-stride lda) @ Bt[N,K]^T ----------------
template<int OUTF32>
__global__ __launch_bounds__(256) void gemm_bt(
    const unsigned short* __restrict__ A, int lda,
    const unsigned short* __restrict__ Bt,
    void* __restrict__ Cv, int ldc, int N, int K)
{
  __shared__ unsigned short As[128 * 32];
  __shared__ unsigned short Bs[128 * 32];
  int tid = threadIdx.x;

  int gx = gridDim.x;
  int nwg = gx * gridDim.y;
  int lin = blockIdx.x + gx * blockIdx.y;
  int q8 = nwg >> 3;
  int nl = (lin & 7) * q8 + (lin >> 3);
  int m0 = (nl / gx) * 128, n0 = (nl % gx) * 128;

  int lane = tid & 63, w = tid >> 6;
  int wr = (w >> 1) * 64, wc = (w & 1) * 64;
  int mr = lane & 15, kg = lane >> 4;

  const unsigned short* Ag = A  + (size_t)(m0 + (tid >> 2)) * lda + ((tid & 3) << 3);
  const unsigned short* Bg = Bt + (size_t)(n0 + (tid >> 2)) * K + ((tid & 3) << 3);

  f32x4 acc[4][4];
  #pragma unroll
  for (int i = 0; i < 4; i++)
    #pragma unroll
    for (int j = 0; j < 4; j++)
      acc[i][j] = (f32x4){0.f, 0.f, 0.f, 0.f};

  for (int k0 = 0; k0 < K; k0 += 32) {
    #pragma unroll
    for (int j = 0; j < 2; j++) {
      GLOAD16(Ag + (size_t)j * 64 * lda, &As[j * 2048 + tid * 8]);
      GLOAD16(Bg + (size_t)j * 64 * K, &Bs[j * 2048 + tid * 8]);
    }
    Ag += 32; Bg += 32;
    __syncthreads();
    short8 af[4], bf[4];
    #pragma unroll
    for (int i = 0; i < 4; i++)
      af[i] = *(const short8*)&As[(wr + i * 16 + mr) * 32 + kg * 8];
    #pragma unroll
    for (int j = 0; j < 4; j++)
      bf[j] = *(const short8*)&Bs[(wc + j * 16 + mr) * 32 + kg * 8];
    __builtin_amdgcn_s_setprio(1);
    #pragma unroll
    for (int i = 0; i < 4; i++)
      #pragma unroll
      for (int j = 0; j < 4; j++)
        acc[i][j] = __builtin_amdgcn_mfma_f32_16x16x32_bf16(af[i], bf[j], acc[i][j], 0, 0, 0);
    __builtin_amdgcn_s_setprio(0);
    __syncthreads();
  }

  if (OUTF32) {
    float* C = (float*)Cv;
    #pragma unroll
    for (int i = 0; i < 4; i++)
      #pragma unroll
      for (int j = 0; j < 4; j++)
        #pragma unroll
        for (int r = 0; r < 4; r++) {
          int row = m0 + wr + i * 16 + kg * 4 + r;
          int col = n0 + wc + j * 16 + mr;
          C[(size_t)row * ldc + col] = acc[i][j][r];
        }
  } else {
    unsigned short* C = (unsigned short*)Cv;
    #pragma unroll
    for (int i = 0; i < 4; i++)
      #pragma unroll
      for (int j = 0; j < 4; j++)
        #pragma unroll
        for (int r = 0; r < 4; r++) {
          int row = m0 + wr + i * 16 + kg * 4 + r;
          int col = n0 + wc + j * 16 + mr;
          C[(size_t)row * ldc + col] = f2b_hw(acc[i][j][r]);
        }
  }
}

// ---------------- assemble q,k head-major with RoPE ----------------
// qc:[4096,1024] | projall: qp at +1024, kp at +2048, ld 3072 | kc: kcv+0 ld 3072
__global__ void assemble_qk(const unsigned short* __restrict__ qc,
                            const unsigned short* __restrict__ projall,
                            const unsigned short* __restrict__ kcv,
                            unsigned short* __restrict__ qh,
                            unsigned short* __restrict__ kh){
  int row = blockIdx.x * 2 + threadIdx.y;
  int d = threadIdx.x;                      // 0..127
  int bh = row >> 11;
  int t  = row & (T_ - 1);
  int b = bh / H_, h = bh % H_;
  size_t srow = (size_t)b * T_ + t;
  size_t dst = ((size_t)bh * T_ + t) * 128 + d;
  if (d < 64) {
    qh[dst] = qc[srow * 1024 + h * 64 + d];
    kh[dst] = kcv[srow * 3072 + h * 64 + d];
  } else {
    int i = d - 64;
    int j = i & 31;
    float invf = exp2f(-(float)j * 0.4152410118750f);
    float f = (float)t * invf;
    float s, c;
    sincosf(f, &s, &c);
    float qx1 = b2f(projall[srow * 3072 + 1024 + h * 64 + j]);
    float qx2 = b2f(projall[srow * 3072 + 1024 + h * 64 + j + 32]);
    float kx1 = b2f(projall[srow * 3072 + 2048 + h * 64 + j]);
    float kx2 = b2f(projall[srow * 3072 + 2048 + h * 64 + j + 32]);
    float qv = (i < 32) ? (qx1 * c - qx2 * s) : (qx1 * s + qx2 * c);
    float kv = (i < 32) ? (kx1 * c - kx2 * s) : (kx1 * s + kx2 * c);
    qh[dst] = f2b_hw(qv);
    kh[dst] = f2b_hw(kv);
  }
}

// ---------------- transpose v: kcv cols [1024:3072] -> vt [B,H,128,T] ----------------
__global__ void vtrans(const unsigned short* __restrict__ kcv,
                       unsigned short* __restrict__ vt){
  __shared__ unsigned short tile[32][33];
  int bh = blockIdx.z;
  int b = bh / H_, h = bh % H_;
  const unsigned short* src = kcv + (size_t)b * T_ * 3072 + 1024 + h * HD_;
  unsigned short* dst = vt + (size_t)bh * HD_ * T_;
  int t0 = blockIdx.x * 32, d0 = blockIdx.y * 32;
  int tx = threadIdx.x, ty = threadIdx.y;
  #pragma unroll
  for (int r = ty; r < 32; r += 8)
    tile[r][tx] = src[(size_t)(t0 + r) * 3072 + d0 + tx];
  __syncthreads();
  #pragma unroll
  for (int r = ty; r < 32; r += 8)
    dst[(size_t)(d0 + r) * T_ + t0 + tx] = tile[tx][r];
}

// ---------------- causal flash attention, reg-staged K/V + raw-barrier pipeline ----------------
__global__ __launch_bounds__(256, 2) void attn_fwd3(
    const unsigned short* __restrict__ qh,
    const unsigned short* __restrict__ kh,
    const unsigned short* __restrict__ vt,
    unsigned short* __restrict__ ao)
{
  __shared__ __align__(16) unsigned short Ks[2][64 * 128];  // [kv][d] swizzled
  __shared__ __align__(16) unsigned short Vs[2][128 * 64];  // [d][kv] swizzled

  const int tid  = threadIdx.x;
  const int lane = tid & 63, w = tid >> 6;
  const int l31  = lane & 31, hi = lane >> 5;
  const int bh = blockIdx.y;
  const int b  = bh >> 4, hd = bh & 15;
  int qt = blockIdx.x;
  if (blockIdx.y >= 16) qt = 15 - qt;            // pair long+short tiles per CU
  const int q0    = qt * 128;
  const int q0w   = q0 + w * 32;
  const int qg    = q0w + l31;
  const int qmaxw = q0w + 31;
  const int nt    = 2 * qt + 2;

  const unsigned short* Qg = qh + (size_t)bh * T_ * 128;
  const unsigned short* Kg = kh + (size_t)bh * T_ * 128;
  const unsigned short* Vg = vt + (size_t)bh * 128 * T_;

  short8 qf[8];
  #pragma unroll
  for (int kc = 0; kc < 8; kc++)
    qf[kc] = *(const short8*)&Qg[(size_t)qg * 128 + kc * 16 + hi * 8];

  f32x16 accO[4];
  #pragma unroll
  for (int sb = 0; sb < 4; sb++)
    #pragma unroll
    for (int r = 0; r < 16; r++) accO[sb][r] = 0.f;

  float m = -1e30f, lsum = 0.f;
  const float SC = 0.12751743f;   // (1/sqrt(128)) * log2(e)

  // staging coordinates (per wave: 4 K rows + 4 V rows, 16B per lane)
  int krow[4], kwof[4], vrow[4], vwof[4];
  #pragma unroll
  for (int j = 0; j < 4; j++){
    int r_ = (w * 4 + j) * 4 + (lane >> 4);
    krow[j] = r_;
    kwof[j] = r_ * 128 + ((((lane & 15) * 16) ^ ((r_ & 7) << 4)) >> 1);
    int d_ = (w * 4 + j) * 8 + (lane >> 3);
    vrow[j] = d_;
    vwof[j] = d_ * 64 + ((((lane & 7) * 16) ^ ((d_ & 7) << 4)) >> 1);
  }
  const int kcol = (lane & 15) * 8;
  const int vcol = (lane & 7) * 8;

  uint4 kst[4], vst[4];

#define REG_LOAD(kvt) do {                                                    \
    int kv0s = (kvt) * 64;                                                    \
    _Pragma("unroll")                                                         \
    for (int j_ = 0; j_ < 4; j_++) {                                          \
      kst[j_] = *(const uint4*)&Kg[(size_t)(kv0s + krow[j_]) * 128 + kcol];   \
      vst[j_] = *(const uint4*)&Vg[(size_t)vrow[j_] * T_ + kv0s + vcol];      \
    }                                                                         \
  } while (0)

#define DS_WRITE(bufi) do {                                                   \
    _Pragma("unroll")                                                         \
    for (int j_ = 0; j_ < 4; j_++) {                                          \
      *(uint4*)&Ks[bufi][kwof[j_]] = kst[j_];                                 \
      *(uint4*)&Vs[bufi][vwof[j_]] = vst[j_];                                 \
    }                                                                         \
  } while (0)

  // prologue: tile0 -> LDS buf0, tile1 -> regs
  REG_LOAD(0);
  DS_WRITE(0);
  if (nt > 1) REG_LOAD(1);
  asm volatile("s_waitcnt lgkmcnt(0)" ::: "memory");
  __builtin_amdgcn_s_barrier();
  __builtin_amdgcn_sched_barrier(0);

  for (int t = 0; t < nt; t++) {
    const int cur = t & 1;
    if (t + 1 < nt) DS_WRITE(cur ^ 1);   // publish tile t+1 (regs -> LDS)
    if (t + 2 < nt) REG_LOAD(t + 2);     // issue tile t+2 (async, hides under compute)
    const int kv0 = t * 64;
    if (kv0 <= qmaxw) {
      const unsigned short* Kb = &Ks[cur][0];
      const unsigned short* Vb = &Vs[cur][0];

      // ---- QK^T (swapped): S^T[kv][q], lane owns q col ----
      f32x16 sa0, sa1;
      #pragma unroll
      for (int r = 0; r < 16; r++) { sa0[r] = 0.f; sa1[r] = 0.f; }
      __builtin_amdgcn_s_setprio(1);
      #pragma unroll
      for (int kc = 0; kc < 8; kc++) {
        int co = (kc * 32 + hi * 16);
        int r0 = l31;
        short8 kf0 = *(const short8*)&Kb[r0 * 128 + ((co ^ ((r0 & 7) << 4)) >> 1)];
        sa0 = __builtin_amdgcn_mfma_f32_32x32x16_bf16(kf0, qf[kc], sa0, 0, 0, 0);
        int r1 = 32 + l31;
        short8 kf1 = *(const short8*)&Kb[r1 * 128 + ((co ^ ((r1 & 7) << 4)) >> 1)];
        sa1 = __builtin_amdgcn_mfma_f32_32x32x16_bf16(kf1, qf[kc], sa1, 0, 0, 0);
      }
      __builtin_amdgcn_s_setprio(0);

      // ---- lane-local softmax (exp2 domain) ----
      float p0[16], p1[16];
      float pmax = -1e30f;
      bool needMask = (kv0 + 63 > q0w);
      if (needMask) {
        #pragma unroll
        for (int r = 0; r < 16; r++) {
          int crow = (r & 3) + 8 * (r >> 2) + 4 * hi;
          float v0 = sa0[r] * SC;
          float v1 = sa1[r] * SC;
          if (kv0 + crow > qg)      v0 = -1e30f;
          if (kv0 + 32 + crow > qg) v1 = -1e30f;
          p0[r] = v0; p1[r] = v1;
          pmax = fmaxf(pmax, fmaxf(v0, v1));
        }
      } else {
        #pragma unroll
        for (int r = 0; r < 16; r++) {
          float v0 = sa0[r] * SC;
          float v1 = sa1[r] * SC;
          p0[r] = v0; p1[r] = v1;
          pmax = fmaxf(pmax, fmaxf(v0, v1));
        }
      }
      pmax = fmaxf(pmax, __shfl_xor(pmax, 32, 64));
      if (!__all(pmax <= m + 8.f)) {     // T13 defer-max
        float mn  = fmaxf(m, pmax);
        float fac = exp2f(m - mn);
        m = mn;
        lsum *= fac;
        #pragma unroll
        for (int sb = 0; sb < 4; sb++)
          #pragma unroll
          for (int r = 0; r < 16; r++) accO[sb][r] *= fac;
      }
      float ls = 0.f;
      #pragma unroll
      for (int r = 0; r < 16; r++) {
        p0[r] = exp2f(p0[r] - m);
        p1[r] = exp2f(p1[r] - m);
        ls += p0[r] + p1[r];
      }
      ls += __shfl_xor(ls, 32, 64);
      lsum += ls;

      // ---- PV: O^T[d][q] += V^T-frag x P-frag ----
      #pragma unroll
      for (int kc2 = 0; kc2 < 4; kc2++) {
        const int c2 = kc2 & 1;
        short8 pa;
        #pragma unroll
        for (int j = 0; j < 4; j++) {
          float a  = (kc2 < 2) ? p0[8 * c2 + j]     : p1[8 * c2 + j];
          float bv = (kc2 < 2) ? p0[8 * c2 + 4 + j] : p1[8 * c2 + 4 + j];
          float snd = hi ? a : bv;
          float rcv = __shfl_xor(snd, 32, 64);
          float lo = hi ? rcv : a;
          float hh = hi ? bv : rcv;
          pa[j]     = (short)f2b_hw(lo);
          pa[4 + j] = (short)f2b_hw(hh);
        }
        __builtin_amdgcn_s_setprio(1);
        #pragma unroll
        for (int sb = 0; sb < 4; sb++) {
          int d = sb * 32 + l31;
          short8 vf = *(const short8*)&Vb[d * 64 + (((kc2 * 32 + hi * 16) ^ ((d & 7) << 4)) >> 1)];
          accO[sb] = __builtin_amdgcn_mfma_f32_32x32x16_bf16(vf, pa, accO[sb], 0, 0, 0);
        }
        __builtin_amdgcn_s_setprio(0);
      }
    }
    __builtin_amdgcn_sched_barrier(0);
    asm volatile("s_waitcnt lgkmcnt(0)" ::: "memory");
    __builtin_amdgcn_s_barrier();
    __builtin_amdgcn_sched_barrier(0);
  }

  float rl = 1.0f / lsum;
  size_t orow = ((size_t)b * T_ + qg) * (H_*HD_) + hd * 128;
  #pragma unroll
  for (int sb = 0; sb < 4; sb++)
    #pragma unroll
    for (int g = 0; g < 4; g++) {
      ushort4 o;
      o.x = f2b_hw(accO[sb][4 * g + 0] * rl);
      o.y = f2b_hw(accO[sb][4 * g + 1] * rl);
      o.z = f2b_hw(accO[sb][4 * g + 2] * rl);
      o.w = f2b_hw(accO[sb][4 * g + 3] * rl);
      *(ushort4*)&ao[orow + sb * 32 + 8 * g + 4 * hi] = o;
    }
#undef REG_LOAD
#undef DS_WRITE
}

// ---------------- launcher ----------------
extern "C" void kernel_launch(void* const* d_in, const int* in_sizes, int n_in,
                              void* d_out, int out_size, void* d_ws, size_t ws_size,
                              hipStream_t stream)
{
  (void)in_sizes; (void)n_in; (void)out_size; (void)ws_size;
  const float* x        = (const float*)d_in[0];
  const float* Wq_down  = (const float*)d_in[1];
  const float* Wq_up    = (const float*)d_in[2];
  const float* Wq_rope  = (const float*)d_in[3];
  const float* Wkv_down = (const float*)d_in[4];
  const float* Wk_up    = (const float*)d_in[5];
  const float* Wv_up    = (const float*)d_in[6];
  const float* Wk_rope  = (const float*)d_in[7];
  const float* Wo       = (const float*)d_in[8];

  char* ws = (char*)d_ws;
  unsigned short* xb      = (unsigned short*)(ws + 0);          // [4096,2048] 16 MB
  unsigned short* Wdall   = (unsigned short*)(ws + 16777216);   // [3072,2048] 12 MB
  unsigned short* WquT    = (unsigned short*)(ws + 29360128);   // [1024,512]  1 MB
  unsigned short* WkcvT   = (unsigned short*)(ws + 30408704);   // [3072,512]  3 MB
  unsigned short* WoT     = (unsigned short*)(ws + 33554432);   // [2048,2048] 8 MB
  unsigned short* projall = (unsigned short*)(ws + 41943040);   // [4096,3072] 24 MB (lat|qp|kp); reused as ao
  unsigned short* qcbuf   = (unsigned short*)(ws + 67108864);   // [4096,1024] 8 MB
  unsigned short* kcvbuf  = (unsigned short*)(ws + 75497472);   // [4096,3072] 24 MB (kc | v)
  unsigned short* qh      = (unsigned short*)(ws + 100663296);  // [B,H,T,128] 16 MB
  unsigned short* kh      = (unsigned short*)(ws + 117440512);  // 16 MB
  unsigned short* vt      = (unsigned short*)(ws + 134217728);  // [B,H,128,T] 16 MB
  unsigned short* ao      = projall;  // projall dead after assemble_qk

  dim3 tb(32, 8);

  cast_f32_bf16<<<(M_TOT * DM_ / 4 + 255) / 256, 256, 0, stream>>>(x, xb, M_TOT * DM_);

  TT8 tab;
  int blk = 0;
  tab.e[0] = { Wq_down,  Wdall,               DM_, QR_,     blk }; blk += (QR_/32)*(DM_/32);
  tab.e[1] = { Wkv_down, Wdall + 512*2048,    DM_, DL_,     blk }; blk += (DL_/32)*(DM_/32);
  tab.e[2] = { Wq_rope,  Wdall + 1024*2048,   DM_, H_*RD_,  blk }; blk += (H_*RD_/32)*(DM_/32);
  tab.e[3] = { Wk_rope,  Wdall + 2048*2048,   DM_, H_*RD_,  blk }; blk += (H_*RD_/32)*(DM_/32);
  tab.e[4] = { Wq_up,    WquT,                QR_, H_*CD_,  blk }; blk += (H_*CD_/32)*(QR_/32);
  tab.e[5] = { Wk_up,    WkcvT,               DL_, H_*CD_,  blk }; blk += (H_*CD_/32)*(DL_/32);
  tab.e[6] = { Wv_up,    WkcvT + 1024*512,    DL_, H_*HD_,  blk }; blk += (H_*HD_/32)*(DL_/32);
  tab.e[7] = { Wo,       WoT,                 H_*HD_, DM_,  blk }; blk += (DM_/32)*(H_*HD_/32);
  transpose_cast8<<<blk, tb, 0, stream>>>(tab);

  // fused projections: all down+rope in one N=3072 GEMM
  gemm_bt<0><<<dim3(3072/128, M_TOT/128), 256, 0, stream>>>(xb, DM_, Wdall, projall, 3072, 3072, DM_);
  gemm_bt<0><<<dim3(1024/128, M_TOT/128), 256, 0, stream>>>(projall, 3072, WquT, qcbuf, 1024, 1024, QR_);
  gemm_bt<0><<<dim3(3072/128, M_TOT/128), 256, 0, stream>>>(projall + 512, 3072, WkcvT, kcvbuf, 3072, 3072, DL_);

  assemble_qk<<<dim3(B_*H_*T_/2), dim3(128, 2), 0, stream>>>(qcbuf, projall, kcvbuf, qh, kh);
  vtrans<<<dim3(T_/32, HD_/32, B_*H_), tb, 0, stream>>>(kcvbuf, vt);

  attn_fwd3<<<dim3(16, 32), 256, 0, stream>>>(qh, kh, vt, ao);

  gemm_bt<1><<<dim3(DM_/128, M_TOT/128), 256, 0, stream>>>(ao, 2048, WoT, d_out, DM_, DM_, H_*HD_);
}